// Round 7
// baseline (163.550 us; speedup 1.0000x reference)
//
#include <hip/hip_runtime.h>
#include <cstdint>
#include <cstddef>

#define A_N 33600
#define G_N 256
#define C_N 80
#define TOPK 10
#define CAP 2048   // max inside-anchors per GT ~900 (208px box @ 0.0205 anchors/px^2)

// Inputs: float32 (pred_scores, pred_bboxes, anchor_points, gt_bboxes), int32 gt_labels.
// Output (float32 flat): labels[A] | bboxes[A*4] | scores[A*81].

// K1: total_neg[a] = sum_c softplus(scores[a,c]); 4 threads/anchor, float4 loads,
// f64 accumulation (ordering-only quantity; perturbation << selection gaps — absmax 0.0
// verified). Also: assigned[a] = -1, and block 0 zeroes the per-GT candidate counters.
__global__ __launch_bounds__(256) void k1_prep(const float* __restrict__ scores,
                                               float* __restrict__ total_neg,
                                               int* __restrict__ assigned,
                                               int* __restrict__ gcnt) {
    const int tid = threadIdx.x;
    const int a = blockIdx.x * 64 + (tid >> 2);   // grid = A_N/64 = 525 exactly
    const int k = tid & 3;
    if (blockIdx.x == 0) gcnt[tid] = 0;           // 256 counters, one per GT
    const float4* __restrict__ p = (const float4*)(scores + (size_t)a * C_N + k * 20);
    double s = 0.0;
#pragma unroll
    for (int i = 0; i < 5; ++i) {
        float4 v = p[i];
        s += (double)(fmaxf(v.x, 0.f) + log1pf(expf(-fabsf(v.x))));
        s += (double)(fmaxf(v.y, 0.f) + log1pf(expf(-fabsf(v.y))));
        s += (double)(fmaxf(v.z, 0.f) + log1pf(expf(-fabsf(v.z))));
        s += (double)(fmaxf(v.w, 0.f) + log1pf(expf(-fabsf(v.w))));
    }
    s += __shfl_xor(s, 1);   // lanes 4m..4m+3 are in one wave
    s += __shfl_xor(s, 2);
    if (k == 0) {
        total_neg[a] = (float)s;
        assigned[a] = -1;
    }
}

// KB: per-GT candidate lists. grid = G_N*4; block b handles GT (b>>2), anchor chunk (b&3)
// of 8400. Coalesced float2 anchor reads (L2-resident); inside == in_gt (in_center with
// radius 2.5w strictly contains the box). Append order is nondeterministic; selection in
// kC is keyed on (cost, idx) so results are order-independent.
__global__ __launch_bounds__(256) void kB_build(const float* __restrict__ anchor_pts,
                                                const float* __restrict__ gt_boxes,
                                                int* __restrict__ gcnt,
                                                int* __restrict__ cand) {
    const int g = blockIdx.x >> 2;
    const int chunk = blockIdx.x & 3;
    const float4 gb = *(const float4*)(gt_boxes + 4 * g);
    int* __restrict__ cg = cand + (size_t)g * CAP;
    const int lo = chunk * 8400, hi = lo + 8400;
    for (int a = lo + threadIdx.x; a < hi; a += 256) {
        float2 ap = *(const float2*)(anchor_pts + 2 * a);
        if (ap.x >= gb.x && ap.x <= gb.z && ap.y >= gb.y && ap.y <= gb.w) {
            int pos = atomicAdd(&gcnt[g], 1);
            if (pos < CAP) cg[pos] = a;
        }
    }
}

// KC: one block per GT: cost for each candidate, dyn_k, dyn_k argmin rounds
// with (cost, lowest-orig-idx) tie-break, scatter via atomicMax.
__global__ __launch_bounds__(256) void kC_topk(const float* __restrict__ pred_boxes,
                                               const float* __restrict__ scores,
                                               const float* __restrict__ total_neg,
                                               const int* __restrict__ gt_labels,
                                               const float* __restrict__ gt_boxes,
                                               const int* __restrict__ gcnt,
                                               const int* __restrict__ cand,
                                               int* __restrict__ assigned) {
    __shared__ float lcost[CAP];
    __shared__ int   lidx[CAP];
    __shared__ float rv[4];
    __shared__ int   ri[4];
    __shared__ float wv_s;
    __shared__ int   wi_s;
    __shared__ int lpos;
    const int g = blockIdx.x;
    const int tid = threadIdx.x;
    if (tid == 0) lpos = 0;
    __syncthreads();

    const float4 gb = *(const float4*)(gt_boxes + 4 * g);
    const int lbl = gt_labels[g];
    const float area_g = (gb.z - gb.x) * (gb.w - gb.y);
    const int cnt = min(gcnt[g], CAP);
    const int* __restrict__ cg = cand + (size_t)g * CAP;

    for (int i = tid; i < cnt; i += 256) {
        int a = cg[i];
        float4 pb = *(const float4*)(pred_boxes + 4 * a);
        float ltx = fmaxf(pb.x, gb.x), lty = fmaxf(pb.y, gb.y);
        float rbx = fminf(pb.z, gb.z), rby = fminf(pb.w, gb.w);
        float wx = fmaxf(rbx - ltx, 0.f), wy = fmaxf(rby - lty, 0.f);
        float ov = wx * wy;
        float area_p = (pb.z - pb.x) * (pb.w - pb.y);
        float iou = ov / (area_p + area_g - ov + 1e-6f);
        float cost = (total_neg[a] - scores[(size_t)a * C_N + lbl])
                     + 3.0f * (-logf(fmaxf(iou, 1e-7f)));
        lcost[i] = cost;
        lidx[i] = a;
        if (ov > 0.f) atomicAdd(&lpos, 1);
    }
    __syncthreads();
    const int dynk = min(max(lpos, 1), TOPK);

    if (cnt == 0) {
        // all-outside row: f32 cost+1e10 collapses (|cost|<512 = ulp/2) -> ref top_k -> anchor 0
        if (tid == 0) atomicMax(&assigned[0], g);
        return;
    }
    for (int r = 0; r < dynk; ++r) {
        float bv = 3.4e38f; int bi = 0x7FFFFFFF;
        for (int i = tid; i < cnt; i += 256) {
            float v = lcost[i]; int ai = lidx[i];
            if (v < bv || (v == bv && ai < bi)) { bv = v; bi = ai; }
        }
        for (int off = 32; off; off >>= 1) {
            float vv = __shfl_down(bv, off);
            int ii = __shfl_down(bi, off);
            if (vv < bv || (vv == bv && ii < bi)) { bv = vv; bi = ii; }
        }
        if ((tid & 63) == 0) { rv[tid >> 6] = bv; ri[tid >> 6] = bi; }
        __syncthreads();
        if (tid == 0) {
            float v = rv[0]; int i = ri[0];
            for (int w = 1; w < 4; ++w)
                if (rv[w] < v || (rv[w] == v && ri[w] < i)) { v = rv[w]; i = ri[w]; }
            wv_s = v; wi_s = i;
            atomicMax(&assigned[i], g);
        }
        __syncthreads();
        float wv = wv_s; int wi = wi_s;
        for (int i = tid; i < cnt; i += 256) {
            if (lcost[i] == wv && lidx[i] == wi) lcost[i] = 3.4e38f;  // unique per anchor
        }
        __syncthreads();
    }
}

// KD: grid = 525 blocks x 64 anchors. float4 zero-fill of the block's score slab
// (64*81 = 5184 floats = 1296 float4, offset 5184*blockIdx.x is 16B-aligned),
// then per-anchor label/box/score scatter (same block -> ordered by __syncthreads).
__global__ __launch_bounds__(256) void kD_final(const float* __restrict__ pred_boxes,
                                                const int* __restrict__ gt_labels,
                                                const float* __restrict__ gt_boxes,
                                                const int* __restrict__ assigned,
                                                float* __restrict__ out) {
    const int tid = threadIdx.x;
    float4* __restrict__ sc4 = (float4*)(out + 5 * A_N) + (size_t)blockIdx.x * 1296;
    float4 z; z.x = 0.f; z.y = 0.f; z.z = 0.f; z.w = 0.f;
#pragma unroll
    for (int j = 0; j < 6; ++j) {
        int i = j * 256 + tid;
        if (i < 1296) sc4[i] = z;
    }
    __syncthreads();
    if (tid >= 64) return;
    const int a = blockIdx.x * 64 + tid;
    const int g = assigned[a];
    float* lbl_out = out;
    float* box_out = out + A_N;
    float* sc_out = out + 5 * A_N;
    if (g >= 0) {
        int lbl = gt_labels[g];
        lbl_out[a] = (float)lbl;
        float4 gb = *(const float4*)(gt_boxes + 4 * g);
        *(float4*)(box_out + 4 * a) = gb;
        float4 pb = *(const float4*)(pred_boxes + 4 * a);
        float ltx = fmaxf(pb.x, gb.x), lty = fmaxf(pb.y, gb.y);
        float rbx = fminf(pb.z, gb.z), rby = fminf(pb.w, gb.w);
        float wx = fmaxf(rbx - ltx, 0.f), wy = fmaxf(rby - lty, 0.f);
        float ov = wx * wy;
        float area_p = (pb.z - pb.x) * (pb.w - pb.y);
        float area_g = (gb.z - gb.x) * (gb.w - gb.y);
        float iou = ov / (area_p + area_g - ov + 1e-6f);
        sc_out[(size_t)a * 81 + lbl] = iou;
    } else {
        lbl_out[a] = 80.0f;
        float4 zz; zz.x = 0.f; zz.y = 0.f; zz.z = 0.f; zz.w = 0.f;
        *(float4*)(box_out + 4 * a) = zz;
    }
}

extern "C" void kernel_launch(void* const* d_in, const int* in_sizes, int n_in,
                              void* d_out, int out_size, void* d_ws, size_t ws_size,
                              hipStream_t stream) {
    (void)in_sizes; (void)n_in; (void)out_size; (void)ws_size;
    const float* pred_scores = (const float*)d_in[0];
    const float* pred_bboxes = (const float*)d_in[1];
    const float* anchor_pts  = (const float*)d_in[2];
    const int*   gt_labels   = (const int*)d_in[3];
    const float* gt_boxes    = (const float*)d_in[4];
    float* out = (float*)d_out;

    char* ws = (char*)d_ws;
    size_t off = 0;
    int*   cand      = (int*)(ws + off);   off += (size_t)G_N * CAP * 4;  // 2 MB
    float* total_neg = (float*)(ws + off); off += (size_t)A_N * 4;
    int*   assigned  = (int*)(ws + off);   off += (size_t)A_N * 4;
    int*   gcnt      = (int*)(ws + off);   off += (size_t)G_N * 4;

    k1_prep<<<A_N / 64, 256, 0, stream>>>(pred_scores, total_neg, assigned, gcnt);
    kB_build<<<G_N * 4, 256, 0, stream>>>(anchor_pts, gt_boxes, gcnt, cand);
    kC_topk<<<G_N, 256, 0, stream>>>(pred_bboxes, pred_scores, total_neg, gt_labels,
                                     gt_boxes, gcnt, cand, assigned);
    kD_final<<<A_N / 64, 256, 0, stream>>>(pred_bboxes, gt_labels, gt_boxes,
                                           assigned, out);
}

// Round 8
// 105.000 us; speedup vs baseline: 1.5576x; 1.5576x over previous
//
#include <hip/hip_runtime.h>
#include <cstdint>
#include <cstddef>

#define A_N 33600
#define G_N 256
#define C_N 80
#define TOPK 10
#define CAPC 768          // per-(GT,chunk) candidate cap; E[inside/chunk] <= ~225
#define NB_A 525          // role-A blocks (softplus): 525*64 = 33600
#define NB_B (G_N * 4)    // role-B blocks (inside scan): 4 chunks per GT

// Inputs: float32 (pred_scores, pred_bboxes, anchor_points, gt_bboxes), int32 gt_labels.
// Output (float32 flat): labels[A] | bboxes[A*4] | scores[A*81].

// KA: fused prep. Blocks [0,525): total_neg (softplus sum, f64 accum — absmax-0 verified),
// assigned=-1. Blocks [525,1549): per-(GT,chunk) inside-anchor compaction with LDS counter
// (no global atomics, no pre-zero) and ILP-batched float4 loads (fix for R7's 4-VGPR
// one-load-in-flight latency wall: 61us -> ~4us predicted).
__global__ __launch_bounds__(256) void kA(const float* __restrict__ scores,
                                          const float* __restrict__ anchor_pts,
                                          const float* __restrict__ gt_boxes,
                                          float* __restrict__ total_neg,
                                          int* __restrict__ assigned,
                                          int* __restrict__ gcnt4,
                                          int* __restrict__ cand) {
    const int tid = threadIdx.x;
    if (blockIdx.x < NB_A) {
        const int a = blockIdx.x * 64 + (tid >> 2);
        const int k = tid & 3;
        const float4* __restrict__ p = (const float4*)(scores + (size_t)a * C_N + k * 20);
        double s = 0.0;
#pragma unroll
        for (int i = 0; i < 5; ++i) {
            float4 v = p[i];
            s += (double)(fmaxf(v.x, 0.f) + log1pf(expf(-fabsf(v.x))));
            s += (double)(fmaxf(v.y, 0.f) + log1pf(expf(-fabsf(v.y))));
            s += (double)(fmaxf(v.z, 0.f) + log1pf(expf(-fabsf(v.z))));
            s += (double)(fmaxf(v.w, 0.f) + log1pf(expf(-fabsf(v.w))));
        }
        s += __shfl_xor(s, 1);   // lanes 4m..4m+3 share a wave
        s += __shfl_xor(s, 2);
        if (k == 0) {
            total_neg[a] = (float)s;
            assigned[a] = -1;
        }
        return;
    }
    // ---- role B ----
    __shared__ int cnt_s;
    if (tid == 0) cnt_s = 0;
    __syncthreads();
    const int gidx = blockIdx.x - NB_A;
    const int g = gidx >> 2;
    const int chunk = gidx & 3;
    const float4 gb = *(const float4*)(gt_boxes + 4 * g);
    const float4* __restrict__ ap4 = (const float4*)anchor_pts;  // 16800 entries (2 anchors each)
    const int fbase = chunk * 4200;
    int* __restrict__ cg = cand + (size_t)gidx * CAPC;

    int done = 0;
#pragma unroll
    for (int grp = 0; grp < 3; ++grp) {
        const int L = (grp < 2) ? 6 : 5;   // 6+6+5 = 17 rounds cover 4352 >= 4200
        float4 v[6];
#pragma unroll
        for (int t = 0; t < 6; ++t) {
            if (t < L) {
                int idx = (done + t) * 256 + tid;
                v[t] = ap4[min(fbase + idx, 16799)];   // clamped: batched independent loads
            }
        }
#pragma unroll
        for (int t = 0; t < 6; ++t) {
            if (t < L) {
                int idx = (done + t) * 256 + tid;
                if (idx < 4200) {
                    int a0 = (fbase + idx) * 2;
                    if (v[t].x >= gb.x && v[t].x <= gb.z && v[t].y >= gb.y && v[t].y <= gb.w) {
                        int p = atomicAdd(&cnt_s, 1);
                        if (p < CAPC) cg[p] = a0;
                    }
                    if (v[t].z >= gb.x && v[t].z <= gb.z && v[t].w >= gb.y && v[t].w <= gb.w) {
                        int p = atomicAdd(&cnt_s, 1);
                        if (p < CAPC) cg[p] = a0 + 1;
                    }
                }
            }
        }
        done += L;
    }
    __syncthreads();
    if (tid == 0) gcnt4[gidx] = min(cnt_s, CAPC);
}

// KC: one block per GT. Gather 4 chunk-lists into dense LDS, compute costs, dyn_k,
// dyn_k argmin rounds keyed on (exact f32 cost, lowest orig idx) -> order-independent.
__global__ __launch_bounds__(256) void kC_topk(const float* __restrict__ pred_boxes,
                                               const float* __restrict__ scores,
                                               const float* __restrict__ total_neg,
                                               const int* __restrict__ gt_labels,
                                               const float* __restrict__ gt_boxes,
                                               const int* __restrict__ gcnt4,
                                               const int* __restrict__ cand,
                                               int* __restrict__ assigned) {
    __shared__ float lcost[4 * CAPC];
    __shared__ int   lidx[4 * CAPC];
    __shared__ float rv[4];
    __shared__ int   ri[4];
    __shared__ float wv_s;
    __shared__ int   wi_s;
    __shared__ int lpos;
    const int g = blockIdx.x;
    const int tid = threadIdx.x;
    if (tid == 0) lpos = 0;
    __syncthreads();

    const float4 gb = *(const float4*)(gt_boxes + 4 * g);
    const int lbl = gt_labels[g];
    const float area_g = (gb.z - gb.x) * (gb.w - gb.y);

    int c[4], base[4];
    int cnt = 0;
#pragma unroll
    for (int q = 0; q < 4; ++q) {
        c[q] = min(gcnt4[4 * g + q], CAPC);
        base[q] = cnt;
        cnt += c[q];
    }
#pragma unroll
    for (int q = 0; q < 4; ++q) {
        const int* __restrict__ cg = cand + (size_t)(4 * g + q) * CAPC;
        for (int i = tid; i < c[q]; i += 256) {
            int a = cg[i];
            float4 pb = *(const float4*)(pred_boxes + 4 * a);
            float ltx = fmaxf(pb.x, gb.x), lty = fmaxf(pb.y, gb.y);
            float rbx = fminf(pb.z, gb.z), rby = fminf(pb.w, gb.w);
            float wx = fmaxf(rbx - ltx, 0.f), wy = fmaxf(rby - lty, 0.f);
            float ov = wx * wy;
            float area_p = (pb.z - pb.x) * (pb.w - pb.y);
            float iou = ov / (area_p + area_g - ov + 1e-6f);
            float cost = (total_neg[a] - scores[(size_t)a * C_N + lbl])
                         + 3.0f * (-logf(fmaxf(iou, 1e-7f)));
            lcost[base[q] + i] = cost;
            lidx[base[q] + i] = a;
            if (ov > 0.f) atomicAdd(&lpos, 1);
        }
    }
    __syncthreads();
    const int dynk = min(max(lpos, 1), TOPK);

    if (cnt == 0) {
        // all-outside row: f32 cost+1e10 collapses (|cost|<512 = ulp/2) -> ref top_k -> anchor 0
        if (tid == 0) atomicMax(&assigned[0], g);
        return;
    }
    for (int r = 0; r < dynk; ++r) {
        float bv = 3.4e38f; int bi = 0x7FFFFFFF;
        for (int i = tid; i < cnt; i += 256) {
            float v = lcost[i]; int ai = lidx[i];
            if (v < bv || (v == bv && ai < bi)) { bv = v; bi = ai; }
        }
        for (int off = 32; off; off >>= 1) {
            float vv = __shfl_down(bv, off);
            int ii = __shfl_down(bi, off);
            if (vv < bv || (vv == bv && ii < bi)) { bv = vv; bi = ii; }
        }
        if ((tid & 63) == 0) { rv[tid >> 6] = bv; ri[tid >> 6] = bi; }
        __syncthreads();
        if (tid == 0) {
            float v = rv[0]; int i = ri[0];
            for (int w = 1; w < 4; ++w)
                if (rv[w] < v || (rv[w] == v && ri[w] < i)) { v = rv[w]; i = ri[w]; }
            wv_s = v; wi_s = i;
            atomicMax(&assigned[i], g);
        }
        __syncthreads();
        float wv = wv_s; int wi = wi_s;
        for (int i = tid; i < cnt; i += 256) {
            if (lcost[i] == wv && lidx[i] == wi) lcost[i] = 3.4e38f;  // unique per anchor
        }
        __syncthreads();
    }
}

// KD: 525 blocks x 64 anchors. float4 zero of the block's score slab (1296 float4,
// 16B-aligned), then per-anchor label/box/score scatter.
__global__ __launch_bounds__(256) void kD_final(const float* __restrict__ pred_boxes,
                                                const int* __restrict__ gt_labels,
                                                const float* __restrict__ gt_boxes,
                                                const int* __restrict__ assigned,
                                                float* __restrict__ out) {
    const int tid = threadIdx.x;
    float4* __restrict__ sc4 = (float4*)(out + 5 * A_N) + (size_t)blockIdx.x * 1296;
    float4 z; z.x = 0.f; z.y = 0.f; z.z = 0.f; z.w = 0.f;
#pragma unroll
    for (int j = 0; j < 6; ++j) {
        int i = j * 256 + tid;
        if (i < 1296) sc4[i] = z;
    }
    __syncthreads();
    if (tid >= 64) return;
    const int a = blockIdx.x * 64 + tid;
    const int g = assigned[a];
    float* lbl_out = out;
    float* box_out = out + A_N;
    float* sc_out = out + 5 * A_N;
    if (g >= 0) {
        int lbl = gt_labels[g];
        lbl_out[a] = (float)lbl;
        float4 gb = *(const float4*)(gt_boxes + 4 * g);
        *(float4*)(box_out + 4 * a) = gb;
        float4 pb = *(const float4*)(pred_boxes + 4 * a);
        float ltx = fmaxf(pb.x, gb.x), lty = fmaxf(pb.y, gb.y);
        float rbx = fminf(pb.z, gb.z), rby = fminf(pb.w, gb.w);
        float wx = fmaxf(rbx - ltx, 0.f), wy = fmaxf(rby - lty, 0.f);
        float ov = wx * wy;
        float area_p = (pb.z - pb.x) * (pb.w - pb.y);
        float area_g = (gb.z - gb.x) * (gb.w - gb.y);
        float iou = ov / (area_p + area_g - ov + 1e-6f);
        sc_out[(size_t)a * 81 + lbl] = iou;
    } else {
        lbl_out[a] = 80.0f;
        float4 zz; zz.x = 0.f; zz.y = 0.f; zz.z = 0.f; zz.w = 0.f;
        *(float4*)(box_out + 4 * a) = zz;
    }
}

extern "C" void kernel_launch(void* const* d_in, const int* in_sizes, int n_in,
                              void* d_out, int out_size, void* d_ws, size_t ws_size,
                              hipStream_t stream) {
    (void)in_sizes; (void)n_in; (void)out_size; (void)ws_size;
    const float* pred_scores = (const float*)d_in[0];
    const float* pred_bboxes = (const float*)d_in[1];
    const float* anchor_pts  = (const float*)d_in[2];
    const int*   gt_labels   = (const int*)d_in[3];
    const float* gt_boxes    = (const float*)d_in[4];
    float* out = (float*)d_out;

    char* ws = (char*)d_ws;
    size_t off = 0;
    int*   cand      = (int*)(ws + off);   off += (size_t)NB_B * CAPC * 4;  // 3 MB
    float* total_neg = (float*)(ws + off); off += (size_t)A_N * 4;
    int*   assigned  = (int*)(ws + off);   off += (size_t)A_N * 4;
    int*   gcnt4     = (int*)(ws + off);   off += (size_t)NB_B * 4;

    kA<<<NB_A + NB_B, 256, 0, stream>>>(pred_scores, anchor_pts, gt_boxes,
                                        total_neg, assigned, gcnt4, cand);
    kC_topk<<<G_N, 256, 0, stream>>>(pred_bboxes, pred_scores, total_neg, gt_labels,
                                     gt_boxes, gcnt4, cand, assigned);
    kD_final<<<NB_A, 256, 0, stream>>>(pred_bboxes, gt_labels, gt_boxes,
                                       assigned, out);
}